// Round 6
// baseline (3386.084 us; speedup 1.0000x reference)
//
#include <hip/hip_runtime.h>
#include <cstdint>
#include <cstddef>

typedef unsigned int u32;
typedef unsigned short u16;

#define SEQ 512   // x axis0 (scan dimension l)
#define BAT 512   // x axis1 (batch dimension b)
#define DD  128
#define NROWS (SEQ * BAT)
#define RS 256    // u16 stride per row-slot: 512B fp32 slot = 256 u16; bf16 row in first 128

// ---------- bf16 helpers (manual, RNE) ----------
__device__ __forceinline__ u16 f2bf(float f) {
    u32 u = __float_as_uint(f);
    u32 r = (u + 0x7fffu + ((u >> 16) & 1u)) >> 16;
    return (u16)r;
}
__device__ __forceinline__ float bf2f(u16 h) { return __uint_as_float(((u32)h) << 16); }
__device__ __forceinline__ float lo16f(u32 u) { return __uint_as_float(u << 16); }
__device__ __forceinline__ float hi16f(u32 u) { return __uint_as_float(u & 0xffff0000u); }
__device__ __forceinline__ u32 packbf(float a, float b) {
    return ((u32)f2bf(b) << 16) | (u32)f2bf(a);
}

__device__ __forceinline__ float fsilu(float v) { return v / (1.0f + __expf(-v)); }
__device__ __forceinline__ float fsoftplus(float v) {
    return (v > 20.0f) ? v : log1pf(__expf(v));
}

// ============================================================
// K1: xs = rmsnorm(x row l*512+b) @ Win[:, 0:128] -> bf16, stored in the
// first 256B of output slot (b*512+l). Block = one l, loops over b.
// ============================================================
__global__ __launch_bounds__(128) void k_inproj_xs(
        const float* __restrict__ x, const float* __restrict__ norm_w,
        const float* __restrict__ Win, u16* __restrict__ xs) {
    __shared__ u32 wlds[64 * 128];
    __shared__ u32 arow[64];
    const int tid = threadIdx.x;
    const int l = blockIdx.x;
    for (int idx = tid; idx < 64 * 128; idx += 128) {
        const int k2 = idx >> 7, c = idx & 127;
        wlds[idx] = packbf(Win[(2 * k2) * 256 + c], Win[(2 * k2 + 1) * 256 + c]);
    }
    const int c = tid;
    for (int b = 0; b < BAT; ++b) {
        __syncthreads();  // covers wlds staging on first iter; arow reuse after
        if (tid < 64) {
            const float2 v = ((const float2*)(x + ((size_t)l * BAT + b) * DD))[tid];
            float ss = v.x * v.x + v.y * v.y;
            #pragma unroll
            for (int m = 1; m < 64; m <<= 1) ss += __shfl_xor(ss, m);
            const float rs = rsqrtf(ss * (1.0f / DD) + 1e-5f);
            const float2 nw = ((const float2*)norm_w)[tid];
            arow[tid] = packbf(v.x * rs * nw.x, v.y * rs * nw.y);
        }
        __syncthreads();
        float a0 = 0.f, a1 = 0.f, a2 = 0.f, a3 = 0.f;
        #pragma unroll
        for (int k2 = 0; k2 < 64; k2 += 4) {
            { const u32 ap = arow[k2 + 0], wp = wlds[(k2 + 0) * 128 + c];
              a0 += lo16f(ap) * lo16f(wp) + hi16f(ap) * hi16f(wp); }
            { const u32 ap = arow[k2 + 1], wp = wlds[(k2 + 1) * 128 + c];
              a1 += lo16f(ap) * lo16f(wp) + hi16f(ap) * hi16f(wp); }
            { const u32 ap = arow[k2 + 2], wp = wlds[(k2 + 2) * 128 + c];
              a2 += lo16f(ap) * lo16f(wp) + hi16f(ap) * hi16f(wp); }
            { const u32 ap = arow[k2 + 3], wp = wlds[(k2 + 3) * 128 + c];
              a3 += lo16f(ap) * lo16f(wp) + hi16f(ap) * hi16f(wp); }
        }
        xs[((size_t)b * SEQ + l) * RS + c] = f2bf((a0 + a1) + (a2 + a3));
    }
}

// ============================================================
// K2: fused res-recompute + conv + SiLU + x_proj + dt_proj + softplus + scan.
// Block = batch b, thread = channel d. Reads xs bf16 from slot l, writes y
// bf16 over the same slot bytes (thread d touches only element d: safe).
// ============================================================
__global__ __launch_bounds__(128) void k_scan(
        const float* __restrict__ x, const float* __restrict__ norm_w,
        const float* __restrict__ Win, u16* __restrict__ xy,
        const float* __restrict__ conv_w, const float* __restrict__ conv_b,
        const float* __restrict__ xpw, const float* __restrict__ dtw,
        const float* __restrict__ dtb, const float* __restrict__ A_log,
        const float* __restrict__ Dp) {
    __shared__ u32 wres[64 * 128];
    __shared__ u32 arow[64];
    __shared__ float red[2][12];
    const int tid = threadIdx.x;
    const int b = blockIdx.x;
    const int d = tid;
    const int wv = tid >> 6, ln = tid & 63;
    for (int idx = tid; idx < 64 * 128; idx += 128) {
        const int k2 = idx >> 7, c = idx & 127;
        wres[idx] = packbf(Win[(2 * k2) * 256 + 128 + c], Win[(2 * k2 + 1) * 256 + 128 + c]);
    }
    float xp[12];
    #pragma unroll
    for (int j = 0; j < 12; ++j) xp[j] = xpw[d * 12 + j];
    float dw[8];
    #pragma unroll
    for (int r = 0; r < 8; ++r) dw[r] = dtw[r * DD + d];
    const float w0 = conv_w[d * 4 + 0], w1 = conv_w[d * 4 + 1];
    const float w2 = conv_w[d * 4 + 2], w3 = conv_w[d * 4 + 3];
    const float cb = conv_b[d], dtbd = dtb[d];
    const float A0 = -__expf(A_log[d * 2 + 0]);
    const float A1 = -__expf(A_log[d * 2 + 1]);
    const float Dd = Dp[d];
    u16* row = xy + (size_t)b * SEQ * RS;
    float c0 = 0.f, c1 = 0.f, c2 = 0.f, c3 = 0.f, s0 = 0.f, s1 = 0.f;
    for (int l = 0; l < SEQ; ++l) {
        if (tid < 64) {
            const float2 v = ((const float2*)(x + ((size_t)l * BAT + b) * DD))[tid];
            float ss = v.x * v.x + v.y * v.y;
            #pragma unroll
            for (int m = 1; m < 64; m <<= 1) ss += __shfl_xor(ss, m);
            const float rs = rsqrtf(ss * (1.0f / DD) + 1e-5f);
            const float2 nw = ((const float2*)norm_w)[tid];
            arow[tid] = packbf(v.x * rs * nw.x, v.y * rs * nw.y);
        }
        __syncthreads();
        // res_d GEMV (128 MACs)
        float r0 = 0.f, r1 = 0.f, r2 = 0.f, r3 = 0.f;
        #pragma unroll
        for (int k2 = 0; k2 < 64; k2 += 4) {
            { const u32 ap = arow[k2 + 0], wp = wres[(k2 + 0) * 128 + d];
              r0 += lo16f(ap) * lo16f(wp) + hi16f(ap) * hi16f(wp); }
            { const u32 ap = arow[k2 + 1], wp = wres[(k2 + 1) * 128 + d];
              r1 += lo16f(ap) * lo16f(wp) + hi16f(ap) * hi16f(wp); }
            { const u32 ap = arow[k2 + 2], wp = wres[(k2 + 2) * 128 + d];
              r2 += lo16f(ap) * lo16f(wp) + hi16f(ap) * hi16f(wp); }
            { const u32 ap = arow[k2 + 3], wp = wres[(k2 + 3) * 128 + d];
              r3 += lo16f(ap) * lo16f(wp) + hi16f(ap) * hi16f(wp); }
        }
        const float resd = (r0 + r1) + (r2 + r3);
        // conv + SiLU (register window over xs)
        const float xv = bf2f(row[(size_t)l * RS + d]);
        c0 = c1; c1 = c2; c2 = c3; c3 = xv;
        const float xsc = fsilu(w0 * c0 + w1 * c1 + w2 * c2 + w3 * c3 + cb);
        // x_proj: 12 dots over d
        float pj[12];
        #pragma unroll
        for (int j = 0; j < 12; ++j) {
            float p = xsc * xp[j];
            #pragma unroll
            for (int m = 1; m < 64; m <<= 1) p += __shfl_xor(p, m);
            pj[j] = p;
        }
        if (ln == 0) {
            #pragma unroll
            for (int j = 0; j < 12; ++j) red[wv][j] = pj[j];
        }
        __syncthreads();
        float dot[12];
        #pragma unroll
        for (int j = 0; j < 12; ++j) dot[j] = red[0][j] + red[1][j];
        float dpre = dtbd;
        #pragma unroll
        for (int r = 0; r < 8; ++r) dpre += dot[r] * dw[r];
        const float dl = fsoftplus(dpre);
        s0 = __expf(dl * A0) * s0 + dl * dot[8];
        s1 = __expf(dl * A1) * s1 + dl * dot[9];
        const float yv = (s0 * dot[10] + s1 * dot[11] + xsc * Dd) * fsilu(resd);
        row[(size_t)l * RS + d] = f2bf(yv);
    }
}

// ============================================================
// K3: out = y @ Wout + x1, written as FP32 (the reference output dtype).
// fp32 row R exactly covers slot R whose first 256B hold y row R: read y
// to LDS before the barrier, write fp32 after — self-overlap only.
// ============================================================
__global__ __launch_bounds__(256) void k_outproj(
        const u16* __restrict__ yslots, float* __restrict__ out,
        const float* __restrict__ Wout,
        const float* __restrict__ x, const float* __restrict__ norm_w) {
    __shared__ u32 wlds[64 * 128];
    __shared__ u32 arow[2][64];
    __shared__ float rss[2];
    const int tid = threadIdx.x;
    for (int idx = tid; idx < 64 * 128; idx += 256) {
        const int k2 = idx >> 7, c = idx & 127;
        wlds[idx] = packbf(Wout[(2 * k2) * DD + c], Wout[(2 * k2 + 1) * DD + c]);
    }
    const int h = tid >> 7;    // row-group
    const int c = tid & 127;   // output column
    const size_t base = (size_t)blockIdx.x * 512;
    for (int i = 0; i < 256; ++i) {
        const size_t R = base + 2 * i + h;
        __syncthreads();  // covers wlds on first iter; protects arow/rss + in-place slot
        if (c < 64) {
            const int lane = c;
            const u16* yr = yslots + R * RS;
            arow[h][lane] = ((u32)yr[2 * lane + 1] << 16) | (u32)yr[2 * lane];
            const float2 v = ((const float2*)(x + R * DD))[lane];
            float ss = v.x * v.x + v.y * v.y;
            #pragma unroll
            for (int m = 1; m < 64; m <<= 1) ss += __shfl_xor(ss, m);
            if (lane == 0) rss[h] = rsqrtf(ss * (1.0f / DD) + 1e-5f);
        }
        __syncthreads();
        float a0 = 0.f, a1 = 0.f;
        #pragma unroll
        for (int k2 = 0; k2 < 64; k2 += 2) {
            { const u32 ap = arow[h][k2], wp = wlds[k2 * DD + c];
              a0 += lo16f(ap) * lo16f(wp) + hi16f(ap) * hi16f(wp); }
            { const u32 ap = arow[h][k2 + 1], wp = wlds[(k2 + 1) * DD + c];
              a1 += lo16f(ap) * lo16f(wp) + hi16f(ap) * hi16f(wp); }
        }
        const float x1v = x[R * DD + c] * rss[h] * norm_w[c];
        out[R * DD + c] = a0 + a1 + x1v;   // fp32 output
    }
}

extern "C" void kernel_launch(void* const* d_in, const int* in_sizes, int n_in,
                              void* d_out, int out_size, void* d_ws, size_t ws_size,
                              hipStream_t stream) {
    (void)in_sizes; (void)n_in; (void)out_size; (void)d_ws; (void)ws_size;
    const float* x      = (const float*)d_in[0];
    const float* norm_w = (const float*)d_in[1];
    const float* Win    = (const float*)d_in[2];
    const float* conv_w = (const float*)d_in[3];
    const float* conv_b = (const float*)d_in[4];
    const float* xpw    = (const float*)d_in[5];
    const float* dtw    = (const float*)d_in[6];
    const float* dtb    = (const float*)d_in[7];
    const float* A_log  = (const float*)d_in[8];
    const float* Dp     = (const float*)d_in[9];
    const float* Wout   = (const float*)d_in[10];
    float* out = (float*)d_out;        // fp32 output, 512B per row-slot
    u16* slots = (u16*)d_out;          // bf16 xs/y live in first 256B of each slot

    k_inproj_xs<<<dim3(512), dim3(128), 0, stream>>>(x, norm_w, Win, slots);
    k_scan<<<dim3(512), dim3(128), 0, stream>>>(x, norm_w, Win, slots, conv_w, conv_b,
                                                xpw, dtw, dtb, A_log, Dp);
    k_outproj<<<dim3(512), dim3(256), 0, stream>>>(slots, out, Wout, x, norm_w);
}